// Round 2
// baseline (66988.788 us; speedup 1.0000x reference)
//
#include <hip/hip_runtime.h>
#include <hip/hip_cooperative_groups.h>
#include <cstdint>
#include <cstddef>

namespace cg = cooperative_groups;

#define BATCH 128
#define SEQT  512
#define EMB_D 300
#define NU0   256
#define NU1   512
#define NU2   256
#define NDENSE 64

// ---------------------------------------------------------------------------
// GEMM: xg[m][n] = A_row(m)[k] @ W[k][n] + bias[n],  m = tl*128 + b
// MODE 0: A_row(m) = emb[tokens[b*SEQT + t0 + tl]]           (K=300)
// MODE 1: A[m][k]  = hseq[tl][k][b], hseq layout [CH][K][128]
// 128x128 tile, BK=8, 256 threads, 8x8 micro-tile.
// ---------------------------------------------------------------------------
template<int MODE>
__global__ __launch_bounds__(256) void gemm_xg(
    const float* __restrict__ Asrc,          // emb (MODE 0) or hseq (MODE 1)
    const int*   __restrict__ tokens, int t0,
    const float* __restrict__ W,
    const float* __restrict__ bias,
    float* __restrict__ out, int N, int K)
{
    __shared__ __align__(16) float As[8][128];
    __shared__ __align__(16) float Ws[8][128];

    const int tid = threadIdx.x;
    const int m0 = blockIdx.x * 128;
    const int n0 = blockIdx.y * 128;
    const int ty = tid >> 4, tx = tid & 15;

    float acc[8][8] = {};

    for (int k0 = 0; k0 < K; k0 += 8) {
        // ---- stage A ----
        if (MODE == 0) {
            const int ml = tid >> 1;                 // 0..127
            const int m  = m0 + ml;
            const int b  = m & 127, tl = m >> 7;
            const int tok = tokens[b * SEQT + t0 + tl];
            const float* row = Asrc + (size_t)tok * EMB_D;   // 1200B stride: 16B aligned
            const int kq = (tid & 1) * 4;
            const int k  = k0 + kq;
            float4 v = {0.f,0.f,0.f,0.f};
            if (k + 4 <= K) v = *(const float4*)(row + k);
            As[kq+0][ml] = v.x; As[kq+1][ml] = v.y;
            As[kq+2][ml] = v.z; As[kq+3][ml] = v.w;
        } else {
            const int mq = tid & 31, lk = tid >> 5;  // 32 m-quads x 8 k
            const int tl = m0 >> 7;                  // one M-tile == one t
            const int k  = k0 + lk;
            float4 v = {0.f,0.f,0.f,0.f};
            if (k < K) v = *(const float4*)(Asrc + ((size_t)tl * K + k) * 128 + mq * 4);
            *(float4*)&As[lk][mq * 4] = v;
        }
        // ---- stage W [K][N] ----
        {
            const int nq = tid & 31, lk = tid >> 5;
            const int k  = k0 + lk;
            float4 v = {0.f,0.f,0.f,0.f};
            if (k < K) v = *(const float4*)(W + (size_t)k * N + n0 + nq * 4);
            *(float4*)&Ws[lk][nq * 4] = v;
        }
        __syncthreads();

        #pragma unroll
        for (int kk = 0; kk < 8; ++kk) {
            const float4 a0 = *(const float4*)&As[kk][ty * 8];
            const float4 a1 = *(const float4*)&As[kk][ty * 8 + 4];
            const float4 b0 = *(const float4*)&Ws[kk][tx * 8];
            const float4 b1 = *(const float4*)&Ws[kk][tx * 8 + 4];
            const float av[8] = {a0.x,a0.y,a0.z,a0.w,a1.x,a1.y,a1.z,a1.w};
            const float bv[8] = {b0.x,b0.y,b0.z,b0.w,b1.x,b1.y,b1.z,b1.w};
            #pragma unroll
            for (int i = 0; i < 8; ++i)
                #pragma unroll
                for (int j = 0; j < 8; ++j)
                    acc[i][j] += av[i] * bv[j];
        }
        __syncthreads();
    }

    #pragma unroll
    for (int i = 0; i < 8; ++i) {
        const int m = m0 + ty * 8 + i;
        float* op = out + (size_t)m * N + n0 + tx * 8;
        #pragma unroll
        for (int q = 0; q < 2; ++q) {
            float4 o;
            o.x = acc[i][q*4+0] + bias[n0 + tx*8 + q*4 + 0];
            o.y = acc[i][q*4+1] + bias[n0 + tx*8 + q*4 + 1];
            o.z = acc[i][q*4+2] + bias[n0 + tx*8 + q*4 + 2];
            o.w = acc[i][q*4+3] + bias[n0 + tx*8 + q*4 + 3];
            *(float4*)(op + q*4) = o;
        }
    }
}

// ---------------------------------------------------------------------------
// Cooperative whole-sequence LSTM recurrence (CH steps, one grid.sync/step).
// Thread owns (b, j0..j0+3) x k-segment ks. Partial dots reduced over ks
// lanes with shfl_xor. c held in registers (ks==0 lanes). h stored
// transposed [u][128] in global, double-buffered. hseq layout [CH][u][128].
// Block: 8 b-rows x JB j-cols x KS k-segs = 256 threads. Grid: 16 x (U/JB).
// ---------------------------------------------------------------------------
template<int U, int JB, int KS>
__global__ __launch_bounds__(256) void lstm_seq(
    const float* __restrict__ xg,      // [CH][128][4U]
    const float* __restrict__ Umat,    // [U][4U], gates i,f,c,o
    float* __restrict__ h0buf,         // [U][128]
    float* __restrict__ h1buf,         // [U][128]
    float* __restrict__ c_state,       // [U][128]
    float* __restrict__ hseq,          // [CH][U][128] or nullptr
    int CH, int init)
{
    constexpr int JT   = JB / 4;       // j-groups per block
    constexpr int KSEG = U / KS;
    static_assert(JT * KS == 32, "lane layout");
    __shared__ float hs[U * 8];

    cg::grid_group grid = cg::this_grid();

    const int tid = threadIdx.x;
    const int jt  = tid % JT;
    const int ks  = (tid / JT) % KS;
    const int bl  = tid >> 5;                   // 0..7
    const int bbase = blockIdx.x * 8;
    const int b   = bbase + bl;
    const int j0  = blockIdx.y * JB + jt * 4;
    const bool owner = (ks == 0);

    float c[4] = {0.f, 0.f, 0.f, 0.f};
    if (init) {
        if (owner) {
            #pragma unroll
            for (int jj = 0; jj < 4; ++jj) h0buf[(size_t)(j0 + jj) * 128 + b] = 0.f;
        }
    } else if (owner) {
        #pragma unroll
        for (int jj = 0; jj < 4; ++jj) c[jj] = c_state[(size_t)(j0 + jj) * 128 + b];
    }
    grid.sync();

    const float* Ubase = Umat + (size_t)(ks * KSEG) * (4 * U) + j0;

    for (int t = 0; t < CH; ++t) {
        const float* hin = (t & 1) ? h1buf : h0buf;
        float*      hout = (t & 1) ? h0buf : h1buf;

        // stage h_prev rows for this block's 8 b's: hs[k*8 + q*4..] (transposed src)
        for (int idx = tid; idx < U * 2; idx += 256) {
            const int k = idx >> 1, q = idx & 1;
            *(float4*)&hs[k * 8 + q * 4] =
                *(const float4*)(hin + (size_t)k * 128 + bbase + q * 4);
        }
        __syncthreads();

        float ai[4] = {}, af[4] = {}, ag[4] = {}, ao[4] = {};
        const float* Up = Ubase;
        #pragma unroll 4
        for (int kk = 0; kk < KSEG; ++kk) {
            const float hk = hs[(ks * KSEG + kk) * 8 + bl];
            const float4 u0 = *(const float4*)(Up);
            const float4 u1 = *(const float4*)(Up + U);
            const float4 u2 = *(const float4*)(Up + 2 * U);
            const float4 u3 = *(const float4*)(Up + 3 * U);
            ai[0] += hk * u0.x; ai[1] += hk * u0.y; ai[2] += hk * u0.z; ai[3] += hk * u0.w;
            af[0] += hk * u1.x; af[1] += hk * u1.y; af[2] += hk * u1.z; af[3] += hk * u1.w;
            ag[0] += hk * u2.x; ag[1] += hk * u2.y; ag[2] += hk * u2.z; ag[3] += hk * u2.w;
            ao[0] += hk * u3.x; ao[1] += hk * u3.y; ao[2] += hk * u3.z; ao[3] += hk * u3.w;
            Up += 4 * U;
        }

        // reduce partial sums across ks lane bits
        #pragma unroll
        for (int m = JT; m < 32; m <<= 1) {
            #pragma unroll
            for (int jj = 0; jj < 4; ++jj) {
                ai[jj] += __shfl_xor(ai[jj], m);
                af[jj] += __shfl_xor(af[jj], m);
                ag[jj] += __shfl_xor(ag[jj], m);
                ao[jj] += __shfl_xor(ao[jj], m);
            }
        }

        if (owner) {
            #pragma unroll
            for (int jj = 0; jj < 4; ++jj) {
                const size_t xoff = ((size_t)t * 128 + b) * (4 * U) + j0 + jj;
                const float gi = xg[xoff]         + ai[jj];
                const float gf = xg[xoff + U]     + af[jj];
                const float gc = xg[xoff + 2 * U] + ag[jj];
                const float go = xg[xoff + 3 * U] + ao[jj];
                const float i_ = 1.f / (1.f + __expf(-gi));
                const float f_ = 1.f / (1.f + __expf(-gf));
                const float o_ = 1.f / (1.f + __expf(-go));
                const float cc = fmaxf(gc, 0.f);
                c[jj] = f_ * c[jj] + i_ * cc;
                const float hn = o_ * fmaxf(c[jj], 0.f);
                hout[(size_t)(j0 + jj) * 128 + b] = hn;
                if (hseq) hseq[((size_t)t * U + j0 + jj) * 128 + b] = hn;
            }
        }
        grid.sync();
    }

    if (owner) {
        #pragma unroll
        for (int jj = 0; jj < 4; ++jj) c_state[(size_t)(j0 + jj) * 128 + b] = c[jj];
    }
}

// ---------------------------------------------------------------------------
// Head: out[b] = sigmoid( relu(h2[:,b] @ Wd + bd) @ Wc + bc ), h2 is [256][128]
// ---------------------------------------------------------------------------
__global__ __launch_bounds__(64) void head_kernel(
    const float* __restrict__ h2t,   // [256][128] transposed
    const float* __restrict__ Wd,    // [256, 64]
    const float* __restrict__ bd,
    const float* __restrict__ Wc,    // [64, 1]
    const float* __restrict__ bc,
    float* __restrict__ out)
{
    const int b = blockIdx.x;
    const int j = threadIdx.x;       // 0..63
    float a = bd[j];
    #pragma unroll 4
    for (int k = 0; k < NU2; ++k)
        a += h2t[(size_t)k * 128 + b] * Wd[(size_t)k * NDENSE + j];
    a = fmaxf(a, 0.f) * Wc[j];
    #pragma unroll
    for (int off = 32; off > 0; off >>= 1)
        a += __shfl_down(a, off);
    if (j == 0)
        out[b] = 1.f / (1.f + expf(-(a + bc[0])));
}

// ---------------------------------------------------------------------------
extern "C" void kernel_launch(void* const* d_in, const int* in_sizes, int n_in,
                              void* d_out, int out_size, void* d_ws, size_t ws_size,
                              hipStream_t stream)
{
    const int*   tokens = (const int*)  d_in[0];
    const float* emb    = (const float*)d_in[1];
    const float* W0     = (const float*)d_in[2];
    const float* Ur0    = (const float*)d_in[3];
    const float* b0     = (const float*)d_in[4];
    const float* W1     = (const float*)d_in[5];
    const float* Ur1    = (const float*)d_in[6];
    const float* b1     = (const float*)d_in[7];
    const float* W2     = (const float*)d_in[8];
    const float* Ur2    = (const float*)d_in[9];
    const float* b2     = (const float*)d_in[10];
    const float* Wd     = (const float*)d_in[11];
    const float* bd     = (const float*)d_in[12];
    const float* Wc     = (const float*)d_in[13];
    const float* bc     = (const float*)d_in[14];
    float* out = (float*)d_out;

    // time-chunk CH (power of two, even) sized to workspace
    auto need = [](int ch) -> size_t {
        return (size_t)ch * (1 << 20)            // xg (worst: 128*2048*4)
             + (size_t)ch * (128 + 256) * 1024   // hs0 + hs1
             + (size_t)(4 << 20);                // states + slack
    };
    int CH = 128;
    while (CH > 2 && need(CH) > ws_size) CH >>= 1;

    char* p = (char*)d_ws;
    float* xg  = (float*)p;  p += (size_t)CH * 128 * 2048 * 4;
    float* hs0 = (float*)p;  p += (size_t)CH * NU0 * 128 * 4;
    float* hs1 = (float*)p;  p += (size_t)CH * NU1 * 128 * 4;
    float* h0A = (float*)p;  p += NU0 * 128 * 4;
    float* h0B = (float*)p;  p += NU0 * 128 * 4;
    float* c0  = (float*)p;  p += NU0 * 128 * 4;
    float* h1A = (float*)p;  p += NU1 * 128 * 4;
    float* h1B = (float*)p;  p += NU1 * 128 * 4;
    float* c1  = (float*)p;  p += NU1 * 128 * 4;
    float* h2A = (float*)p;  p += NU2 * 128 * 4;
    float* h2B = (float*)p;  p += NU2 * 128 * 4;
    float* c2  = (float*)p;  p += NU2 * 128 * 4;

    const int nc = SEQT / CH;
    for (int ci = 0; ci < nc; ++ci) {
        const int t0 = ci * CH;
        const int init = (ci == 0) ? 1 : 0;

        // ---- layer 0 ----
        gemm_xg<0><<<dim3(CH, (4 * NU0) / 128), 256, 0, stream>>>(
            emb, tokens, t0, W0, b0, xg, 4 * NU0, EMB_D);
        {
            const float* xg_p = xg; const float* U_p = Ur0;
            float *hA = h0A, *hB = h0B, *cp = c0, *hq = hs0;
            int ch = CH, in_ = init;
            void* args[] = {&xg_p, &U_p, &hA, &hB, &cp, &hq, &ch, &in_};
            hipLaunchCooperativeKernel((void*)lstm_seq<NU0, 16, 8>,
                                       dim3(16, NU0 / 16), dim3(256), args, 0, stream);
        }
        // ---- layer 1 ----
        gemm_xg<1><<<dim3(CH, (4 * NU1) / 128), 256, 0, stream>>>(
            hs0, nullptr, 0, W1, b1, xg, 4 * NU1, NU0);
        {
            const float* xg_p = xg; const float* U_p = Ur1;
            float *hA = h1A, *hB = h1B, *cp = c1, *hq = hs1;
            int ch = CH, in_ = init;
            void* args[] = {&xg_p, &U_p, &hA, &hB, &cp, &hq, &ch, &in_};
            hipLaunchCooperativeKernel((void*)lstm_seq<NU1, 32, 4>,
                                       dim3(16, NU1 / 32), dim3(256), args, 0, stream);
        }
        // ---- layer 2 ----
        gemm_xg<1><<<dim3(CH, (4 * NU2) / 128), 256, 0, stream>>>(
            hs1, nullptr, 0, W2, b2, xg, 4 * NU2, NU1);
        {
            const float* xg_p = xg; const float* U_p = Ur2;
            float *hA = h2A, *hB = h2B, *cp = c2, *hq = nullptr;
            int ch = CH, in_ = init;
            void* args[] = {&xg_p, &U_p, &hA, &hB, &cp, &hq, &ch, &in_};
            hipLaunchCooperativeKernel((void*)lstm_seq<NU2, 16, 8>,
                                       dim3(16, NU2 / 16), dim3(256), args, 0, stream);
        }
    }

    // T=512 even -> final h in buffer A (local t restarts each chunk, CH even)
    head_kernel<<<BATCH, 64, 0, stream>>>(h2A, Wd, bd, Wc, bc, out);
}

// Round 3
// 57471.246 us; speedup vs baseline: 1.1656x; 1.1656x over previous
//
#include <hip/hip_runtime.h>
#include <hip/hip_cooperative_groups.h>
#include <cstdint>
#include <cstddef>

namespace cg = cooperative_groups;

#define BATCH 128
#define SEQT  512
#define EMB_D 300
#define NU0   256
#define NU1   512
#define NU2   256
#define NDENSE 64

// ---------------------------------------------------------------------------
// GEMM: xg[m][n] = A_row(m)[k] @ W[k][n] + bias[n],  m = tl*128 + b
// MODE 0: A_row(m) = emb[tokens[b*SEQT + t0 + tl]]           (K=300)
// MODE 1: A[m][k]  = hseq[tl][k][b], hseq layout [CH][K][128]
// 128x128 tile, BK=8, 256 threads, 8x8 micro-tile.
// ---------------------------------------------------------------------------
template<int MODE>
__global__ __launch_bounds__(256) void gemm_xg(
    const float* __restrict__ Asrc,          // emb (MODE 0) or hseq (MODE 1)
    const int*   __restrict__ tokens, int t0,
    const float* __restrict__ W,
    const float* __restrict__ bias,
    float* __restrict__ out, int N, int K)
{
    __shared__ __align__(16) float As[8][128];
    __shared__ __align__(16) float Ws[8][128];

    const int tid = threadIdx.x;
    const int m0 = blockIdx.x * 128;
    const int n0 = blockIdx.y * 128;
    const int ty = tid >> 4, tx = tid & 15;

    float acc[8][8] = {};

    for (int k0 = 0; k0 < K; k0 += 8) {
        if (MODE == 0) {
            const int ml = tid >> 1;                 // 0..127
            const int m  = m0 + ml;
            const int b  = m & 127, tl = m >> 7;
            const int tok = tokens[b * SEQT + t0 + tl];
            const float* row = Asrc + (size_t)tok * EMB_D;
            const int kq = (tid & 1) * 4;
            const int k  = k0 + kq;
            float4 v = {0.f,0.f,0.f,0.f};
            if (k + 4 <= K) v = *(const float4*)(row + k);
            As[kq+0][ml] = v.x; As[kq+1][ml] = v.y;
            As[kq+2][ml] = v.z; As[kq+3][ml] = v.w;
        } else {
            const int mq = tid & 31, lk = tid >> 5;
            const int tl = m0 >> 7;                  // one M-tile == one t
            const int k  = k0 + lk;
            float4 v = {0.f,0.f,0.f,0.f};
            if (k < K) v = *(const float4*)(Asrc + ((size_t)tl * K + k) * 128 + mq * 4);
            *(float4*)&As[lk][mq * 4] = v;
        }
        {
            const int nq = tid & 31, lk = tid >> 5;
            const int k  = k0 + lk;
            float4 v = {0.f,0.f,0.f,0.f};
            if (k < K) v = *(const float4*)(W + (size_t)k * N + n0 + nq * 4);
            *(float4*)&Ws[lk][nq * 4] = v;
        }
        __syncthreads();

        #pragma unroll
        for (int kk = 0; kk < 8; ++kk) {
            const float4 a0 = *(const float4*)&As[kk][ty * 8];
            const float4 a1 = *(const float4*)&As[kk][ty * 8 + 4];
            const float4 b0 = *(const float4*)&Ws[kk][tx * 8];
            const float4 b1 = *(const float4*)&Ws[kk][tx * 8 + 4];
            const float av[8] = {a0.x,a0.y,a0.z,a0.w,a1.x,a1.y,a1.z,a1.w};
            const float bv[8] = {b0.x,b0.y,b0.z,b0.w,b1.x,b1.y,b1.z,b1.w};
            #pragma unroll
            for (int i = 0; i < 8; ++i)
                #pragma unroll
                for (int j = 0; j < 8; ++j)
                    acc[i][j] += av[i] * bv[j];
        }
        __syncthreads();
    }

    #pragma unroll
    for (int i = 0; i < 8; ++i) {
        const int m = m0 + ty * 8 + i;
        float* op = out + (size_t)m * N + n0 + tx * 8;
        #pragma unroll
        for (int q = 0; q < 2; ++q) {
            float4 o;
            o.x = acc[i][q*4+0] + bias[n0 + tx*8 + q*4 + 0];
            o.y = acc[i][q*4+1] + bias[n0 + tx*8 + q*4 + 1];
            o.z = acc[i][q*4+2] + bias[n0 + tx*8 + q*4 + 2];
            o.w = acc[i][q*4+3] + bias[n0 + tx*8 + q*4 + 3];
            *(float4*)(op + q*4) = o;
        }
    }
}

// ---------------------------------------------------------------------------
// Persistent LSTM recurrence. U slice staged to LDS ONCE (survives grid.sync
// -> never re-fetched from HBM after the per-step fence). Each WG owns
// BW batch rows x HC h-cols with FULL k range (KH-way k-split inside the
// wave when BW*HC < 256): no cross-WG reduction. c in registers.
// Thread map: tid = jl*32 + (kh*16|bl) -> h/hseq writes coalesced over b.
// LDS: Ulds[4][HC][U+4] (per-gate k-major rows, b128 reads, 32-way bcast),
//      hs[BW][U+4]      (h of own batch rows, padded +4 words).
// h ping-pong in global [128][U]; hseq [CH][U][128] feeds next layer's GEMM.
// ---------------------------------------------------------------------------
template<int U_, int BW, int HC, int KH>
__global__ __launch_bounds__(256) void lstm_seq(
    const float* __restrict__ xg,    // [CH][128][4U]
    const float* __restrict__ Umat,  // [U][4U] gates i,f,c,o
    float* __restrict__ hA,          // [128][U]
    float* __restrict__ hB,          // [128][U]
    float* __restrict__ cst,         // [128][U]
    float* __restrict__ hseq,        // [CH][U][128] or nullptr
    int CH, int init)
{
    static_assert(HC == 8, "staging maps assume 4*HC==32");
    static_assert(BW * HC * KH == 256, "thread map");
    constexpr int UP = U_ + 4;
    extern __shared__ float smem[];
    float* Ulds = smem;                 // [4][HC][UP]
    float* hs   = smem + 4 * HC * UP;   // [BW][UP]

    cg::grid_group grid = cg::this_grid();
    const int tid = threadIdx.x;
    const int jl  = tid >> 5;
    const int r   = tid & 31;
    const int kh  = (KH == 2) ? (r >> 4) : 0;
    const int bl  = (KH == 2) ? (r & 15) : r;
    const int b0  = blockIdx.x * BW;
    const int j0  = blockIdx.y * HC;
    const int b   = b0 + bl;
    const int j   = j0 + jl;
    const bool owner = (KH == 1) || (kh == 0);

    // ---- stage U slice into LDS (once per launch) ----
    for (int i = tid; i < 4 * HC * U_; i += 256) {
        const int k   = i >> 5;          // 4*HC == 32
        const int gcl = i & 31;
        const int g = gcl >> 3, hc = gcl & 7;
        Ulds[(g * HC + hc) * UP + k] = Umat[(size_t)k * (4 * U_) + g * U_ + j0 + hc];
    }
    float c = 0.f;
    if (!init && owner) c = cst[(size_t)b * U_ + j];
    __syncthreads();

    constexpr int KSEG = U_ / KH;
    constexpr int NI   = KSEG / 4;
    const int koff = kh * KSEG;

    for (int t = 0; t < CH; ++t) {
        const float* hin = (t & 1) ? hB : hA;
        float*      hout = (t & 1) ? hA : hB;

        // ---- stage h_prev rows (coalesced float4) ----
        if (t == 0 && init) {
            for (int i = tid; i < BW * (U_ / 4); i += 256) {
                const int row = i / (U_ / 4), c4 = i % (U_ / 4);
                *(float4*)&hs[row * UP + c4 * 4] = float4{0.f, 0.f, 0.f, 0.f};
            }
        } else {
            for (int i = tid; i < BW * (U_ / 4); i += 256) {
                const int row = i / (U_ / 4), c4 = i % (U_ / 4);
                *(float4*)&hs[row * UP + c4 * 4] =
                    *(const float4*)&hin[(size_t)(b0 + row) * U_ + c4 * 4];
            }
        }
        __syncthreads();

        // ---- 4-gate dot over own k segment, all from LDS ----
        float a0 = 0.f, a1 = 0.f, a2 = 0.f, a3 = 0.f;
        const float* hp  = &hs[bl * UP + koff];
        const float* u0p = &Ulds[(0 * HC + jl) * UP + koff];
        const float* u1p = &Ulds[(1 * HC + jl) * UP + koff];
        const float* u2p = &Ulds[(2 * HC + jl) * UP + koff];
        const float* u3p = &Ulds[(3 * HC + jl) * UP + koff];
        #pragma unroll 4
        for (int q = 0; q < NI; ++q) {
            const float4 hv = *(const float4*)(hp  + q * 4);
            const float4 x0 = *(const float4*)(u0p + q * 4);
            const float4 x1 = *(const float4*)(u1p + q * 4);
            const float4 x2 = *(const float4*)(u2p + q * 4);
            const float4 x3 = *(const float4*)(u3p + q * 4);
            a0 = fmaf(hv.x, x0.x, fmaf(hv.y, x0.y, fmaf(hv.z, x0.z, fmaf(hv.w, x0.w, a0))));
            a1 = fmaf(hv.x, x1.x, fmaf(hv.y, x1.y, fmaf(hv.z, x1.z, fmaf(hv.w, x1.w, a1))));
            a2 = fmaf(hv.x, x2.x, fmaf(hv.y, x2.y, fmaf(hv.z, x2.z, fmaf(hv.w, x2.w, a2))));
            a3 = fmaf(hv.x, x3.x, fmaf(hv.y, x3.y, fmaf(hv.z, x3.z, fmaf(hv.w, x3.w, a3))));
        }
        if (KH == 2) {
            a0 += __shfl_xor(a0, 16);
            a1 += __shfl_xor(a1, 16);
            a2 += __shfl_xor(a2, 16);
            a3 += __shfl_xor(a3, 16);
        }

        if (owner) {
            const size_t xo = ((size_t)t * 128 + b) * (4 * U_) + j;
            const float gi = xg[xo]            + a0;
            const float gf = xg[xo + U_]       + a1;
            const float gc = xg[xo + 2 * U_]   + a2;
            const float go = xg[xo + 3 * U_]   + a3;
            const float i_ = 1.f / (1.f + __expf(-gi));
            const float f_ = 1.f / (1.f + __expf(-gf));
            const float o_ = 1.f / (1.f + __expf(-go));
            const float cand = fmaxf(gc, 0.f);
            c = f_ * c + i_ * cand;
            const float hn = o_ * fmaxf(c, 0.f);
            hout[(size_t)b * U_ + j] = hn;
            if (hseq) hseq[((size_t)t * U_ + j) * 128 + b] = hn;
        }
        grid.sync();   // also covers hs reuse across iterations
    }

    if (owner) cst[(size_t)b * U_ + j] = c;
}

// ---------------------------------------------------------------------------
// Head: out[b] = sigmoid( relu(h2[b,:] @ Wd + bd) @ Wc + bc ), h2 [128][256]
// ---------------------------------------------------------------------------
__global__ __launch_bounds__(64) void head_kernel(
    const float* __restrict__ h2,
    const float* __restrict__ Wd,    // [256, 64]
    const float* __restrict__ bd,
    const float* __restrict__ Wc,    // [64, 1]
    const float* __restrict__ bc,
    float* __restrict__ out)
{
    const int b = blockIdx.x;
    const int j = threadIdx.x;       // 0..63
    float a = bd[j];
    const float* hrow = h2 + (size_t)b * NU2;
    #pragma unroll 4
    for (int k = 0; k < NU2; ++k)
        a += hrow[k] * Wd[(size_t)k * NDENSE + j];
    a = fmaxf(a, 0.f) * Wc[j];
    #pragma unroll
    for (int off = 32; off > 0; off >>= 1)
        a += __shfl_down(a, off);
    if (j == 0)
        out[b] = 1.f / (1.f + expf(-(a + bc[0])));
}

// ---------------------------------------------------------------------------
extern "C" void kernel_launch(void* const* d_in, const int* in_sizes, int n_in,
                              void* d_out, int out_size, void* d_ws, size_t ws_size,
                              hipStream_t stream)
{
    const int*   tokens = (const int*)  d_in[0];
    const float* emb    = (const float*)d_in[1];
    const float* W0     = (const float*)d_in[2];
    const float* Ur0    = (const float*)d_in[3];
    const float* b0     = (const float*)d_in[4];
    const float* W1     = (const float*)d_in[5];
    const float* Ur1    = (const float*)d_in[6];
    const float* b1     = (const float*)d_in[7];
    const float* W2     = (const float*)d_in[8];
    const float* Ur2    = (const float*)d_in[9];
    const float* b2     = (const float*)d_in[10];
    const float* Wd     = (const float*)d_in[11];
    const float* bd     = (const float*)d_in[12];
    const float* Wc     = (const float*)d_in[13];
    const float* bc     = (const float*)d_in[14];
    float* out = (float*)d_out;

    // time-chunk CH (power of two, even) sized to workspace
    auto need = [](int ch) -> size_t {
        return (size_t)ch * (1 << 20)            // xg (worst: 128*2048*4)
             + (size_t)ch * (128 + 256) * 1024   // hs0 + hs1
             + (size_t)(4 << 20);                // states + slack
    };
    int CH = 128;
    while (CH > 2 && need(CH) > ws_size) CH >>= 1;

    char* p = (char*)d_ws;
    float* xg  = (float*)p;  p += (size_t)CH * 128 * 2048 * 4;
    float* hs0 = (float*)p;  p += (size_t)CH * NU0 * 128 * 4;
    float* hs1 = (float*)p;  p += (size_t)CH * NU1 * 128 * 4;
    float* h0A = (float*)p;  p += NU0 * 128 * 4;
    float* h0B = (float*)p;  p += NU0 * 128 * 4;
    float* c0  = (float*)p;  p += NU0 * 128 * 4;
    float* h1A = (float*)p;  p += NU1 * 128 * 4;
    float* h1B = (float*)p;  p += NU1 * 128 * 4;
    float* c1  = (float*)p;  p += NU1 * 128 * 4;
    float* h2A = (float*)p;  p += NU2 * 128 * 4;
    float* h2B = (float*)p;  p += NU2 * 128 * 4;
    float* c2  = (float*)p;  p += NU2 * 128 * 4;

    // dynamic LDS bytes: Ulds[4][8][U+4] + hs[BW][U+4]
    const unsigned lds_256 = (4 * 8 * (NU0 + 4) + 16 * (NU0 + 4)) * 4;  // 49,920 B
    const unsigned lds_512 = (4 * 8 * (NU1 + 4) + 32 * (NU1 + 4)) * 4;  // 132,096 B

    const int nc = SEQT / CH;
    for (int ci = 0; ci < nc; ++ci) {
        const int t0 = ci * CH;
        int init = (ci == 0) ? 1 : 0;
        int ch = CH;

        // ---- layer 0 ----
        gemm_xg<0><<<dim3(CH, (4 * NU0) / 128), 256, 0, stream>>>(
            emb, tokens, t0, W0, b0, xg, 4 * NU0, EMB_D);
        {
            const float* xg_p = xg; const float* U_p = Ur0;
            float *hA = h0A, *hB = h0B, *cp = c0, *hq = hs0;
            void* args[] = {&xg_p, &U_p, &hA, &hB, &cp, &hq, &ch, &init};
            hipLaunchCooperativeKernel((void*)lstm_seq<NU0, 16, 8, 2>,
                                       dim3(128 / 16, NU0 / 8), dim3(256), args, lds_256, stream);
        }
        // ---- layer 1 ----
        gemm_xg<1><<<dim3(CH, (4 * NU1) / 128), 256, 0, stream>>>(
            hs0, nullptr, 0, W1, b1, xg, 4 * NU1, NU0);
        {
            const float* xg_p = xg; const float* U_p = Ur1;
            float *hA = h1A, *hB = h1B, *cp = c1, *hq = hs1;
            void* args[] = {&xg_p, &U_p, &hA, &hB, &cp, &hq, &ch, &init};
            hipLaunchCooperativeKernel((void*)lstm_seq<NU1, 32, 8, 1>,
                                       dim3(128 / 32, NU1 / 8), dim3(256), args, lds_512, stream);
        }
        // ---- layer 2 ----
        gemm_xg<1><<<dim3(CH, (4 * NU2) / 128), 256, 0, stream>>>(
            hs1, nullptr, 0, W2, b2, xg, 4 * NU2, NU1);
        {
            const float* xg_p = xg; const float* U_p = Ur2;
            float *hA = h2A, *hB = h2B, *cp = c2, *hq = nullptr;
            void* args[] = {&xg_p, &U_p, &hA, &hB, &cp, &hq, &ch, &init};
            hipLaunchCooperativeKernel((void*)lstm_seq<NU2, 16, 8, 2>,
                                       dim3(128 / 16, NU2 / 8), dim3(256), args, lds_256, stream);
        }
    }

    // CH even -> final h of layer 2 lands in h2A
    head_kernel<<<BATCH, 64, 0, stream>>>(h2A, Wd, bd, Wc, bc, out);
}

// Round 4
// 18659.093 us; speedup vs baseline: 3.5901x; 3.0801x over previous
//
#include <hip/hip_runtime.h>
#include <cstdint>
#include <cstddef>

#define BATCH 128
#define SEQT  512
#define EMB_D 300
#define NU0   256
#define NU1   512
#define NU2   256
#define NDENSE 64

typedef __attribute__((ext_vector_type(8))) short bf16x8;
typedef __attribute__((ext_vector_type(4))) float f32x4;

static __device__ __forceinline__ unsigned short f2bf(float x) {
    union { float f; unsigned u; } v; v.f = x;
    const unsigned r = v.u + 0x7FFFu + ((v.u >> 16) & 1u);
    return (unsigned short)(r >> 16);
}
static __device__ __forceinline__ float bf2f(unsigned short b) {
    union { unsigned u; float f; } v; v.u = ((unsigned)b) << 16;
    return v.f;
}
static __device__ __forceinline__ float sigmoidf_(float x) {
    return 1.f / (1.f + __expf(-x));
}

// ---------------------------------------------------------------------------
// GEMM producing TRANSPOSED gate pre-activations:
//   xgT[t][m][b] = sum_k W[k][m] * x[t][b][k] + bias[m]
// M-dim = gate columns (NG), N-dim = batch (128). One t per blockIdx.x.
// A-tile = rows of W (coalesced); B-tile:
//   MODE 1: Bsrc = hseqT [CH][K][128]  (coalesced float4 over b)
//   MODE 0: Bsrc = emb, gathered via tokens (row-gather, float4 over k)
// 128(M)x128(N) tile, BK=8, 256 threads, 8x8 micro-tile.
// ---------------------------------------------------------------------------
template<int MODE>
__global__ __launch_bounds__(256) void gemm_xgT(
    const float* __restrict__ Bsrc,
    const int*   __restrict__ tokens, int t0,
    const float* __restrict__ W,
    const float* __restrict__ bias,
    float* __restrict__ out, int NG, int K)
{
    __shared__ __align__(16) float As[8][132];
    __shared__ __align__(16) float Bs[8][132];

    const int tid = threadIdx.x;
    const int t  = blockIdx.x;
    const int m0 = blockIdx.y * 128;
    const int ty = tid >> 4, tx = tid & 15;

    int tok = 0;
    if (MODE == 0) tok = tokens[(tid & 127) * SEQT + t0 + t];

    float acc[8][8] = {};

    for (int k0 = 0; k0 < K; k0 += 8) {
        {   // A: As[k][m] = W[k0+k][m0+m]
            const int mq = tid & 31, lk = tid >> 5;
            float4 v = {0.f, 0.f, 0.f, 0.f};
            if (k0 + lk < K) v = *(const float4*)(W + (size_t)(k0 + lk) * NG + m0 + mq * 4);
            *(float4*)&As[lk][mq * 4] = v;
        }
        if (MODE == 1) {
            const int bq = tid & 31, lk = tid >> 5;
            float4 v = {0.f, 0.f, 0.f, 0.f};
            if (k0 + lk < K) v = *(const float4*)(Bsrc + ((size_t)t * K + k0 + lk) * 128 + bq * 4);
            *(float4*)&Bs[lk][bq * 4] = v;
        } else {
            const int b = tid & 127, kh = tid >> 7;     // kh 0..1
            const int k = k0 + kh * 4;
            float4 v = {0.f, 0.f, 0.f, 0.f};
            if (k + 4 <= K) v = *(const float4*)(Bsrc + (size_t)tok * EMB_D + k);
            Bs[kh * 4 + 0][b] = v.x; Bs[kh * 4 + 1][b] = v.y;
            Bs[kh * 4 + 2][b] = v.z; Bs[kh * 4 + 3][b] = v.w;
        }
        __syncthreads();

        #pragma unroll
        for (int kk = 0; kk < 8; ++kk) {
            const float4 a0 = *(const float4*)&As[kk][ty * 8];
            const float4 a1 = *(const float4*)&As[kk][ty * 8 + 4];
            const float4 b0 = *(const float4*)&Bs[kk][tx * 8];
            const float4 b1 = *(const float4*)&Bs[kk][tx * 8 + 4];
            const float av[8] = {a0.x,a0.y,a0.z,a0.w,a1.x,a1.y,a1.z,a1.w};
            const float bv[8] = {b0.x,b0.y,b0.z,b0.w,b1.x,b1.y,b1.z,b1.w};
            #pragma unroll
            for (int i = 0; i < 8; ++i)
                #pragma unroll
                for (int j = 0; j < 8; ++j)
                    acc[i][j] += av[i] * bv[j];
        }
        __syncthreads();
    }

    #pragma unroll
    for (int i = 0; i < 8; ++i) {
        const int m = m0 + ty * 8 + i;
        const float bi = bias[m];
        float* op = out + ((size_t)t * NG + m) * 128 + tx * 8;
        float4 o0, o1;
        o0.x = acc[i][0] + bi; o0.y = acc[i][1] + bi; o0.z = acc[i][2] + bi; o0.w = acc[i][3] + bi;
        o1.x = acc[i][4] + bi; o1.y = acc[i][5] + bi; o1.z = acc[i][6] + bi; o1.w = acc[i][7] + bi;
        *(float4*)op = o0;
        *(float4*)(op + 4) = o1;
    }
}

// ---------------------------------------------------------------------------
// MFMA recurrence. 8 groups x 16 batch rows; group = U/16 WGs of 256 threads.
// Per WG: 16 h-cols (J..J+15) x 4 gates (one per wave). U columns live
// permanently in B-fragments (registers, bf16). Per step: A = h_prev (bf16,
// global, ping-pong), 16x16x32 MFMA chain over K=U, add fp32 xgT, gate
// nonlinearities exchanged through a small LDS tile; wave2 owns c in regs.
// Group-local sense-free barrier: release atomicAdd + acquire spin on a
// per-group epoch counter (zeroed once per kernel_launch call).
// C-frag mapping (m89-verified): col = lane&15, row = (lane>>4)*4 + reg.
// ---------------------------------------------------------------------------
template<int U_>
__global__ __launch_bounds__(256) void lstm_mfma(
    const float* __restrict__ xgT,          // [CH][4U][128]
    const float* __restrict__ Umat,         // [U][4U] gates i,f,c,o
    unsigned short* __restrict__ h0,        // [128][U] bf16 (parity-0 buffer)
    unsigned short* __restrict__ h1,        // [128][U] bf16 (parity-1 buffer)
    float* __restrict__ cst,                // [128][U]
    float* __restrict__ hseqT,              // [CH][U][128] f32 or nullptr
    unsigned* __restrict__ cnt,             // [8] group epoch counters (pre-zeroed)
    int CH, int init)
{
    constexpr int NG  = 4 * U_;
    constexpr int KT  = U_ / 32;     // MFMA K-tiles
    constexpr int WPG = U_ / 16;     // WGs per group

    __shared__ float ex[3][16][17];

    const int tid  = threadIdx.x;
    const int wv   = tid >> 6;          // 0..3 = gate i,f,c,o
    const int lane = tid & 63;
    const int lo   = lane & 15;         // col (j offset / A row m)
    const int hi   = lane >> 4;         // 0..3
    const int g    = blockIdx.x / WPG;
    const int wgj  = blockIdx.x % WPG;
    const int J    = wgj * 16;
    const int b0   = g * 16;
    const int gcol = wv * U_ + J + lo;  // global gate column

    // ---- persistent B-fragments: U[:, gcol] as bf16 ----
    bf16x8 bf[KT];
    #pragma unroll
    for (int kt = 0; kt < KT; ++kt) {
        const float* up = Umat + (size_t)(kt * 32 + hi * 8) * NG + gcol;
        bf16x8 v;
        #pragma unroll
        for (int i = 0; i < 8; ++i) v[i] = (short)f2bf(up[(size_t)i * NG]);
        bf[kt] = v;
    }

    // ---- c state (wave 2 lanes own (b = b0+hi*4+r, j = J+lo)) ----
    float cr0 = 0.f, cr1 = 0.f, cr2 = 0.f, cr3 = 0.f;
    if (!init && wv == 2) {
        cr0 = cst[(size_t)(b0 + hi * 4 + 0) * U_ + J + lo];
        cr1 = cst[(size_t)(b0 + hi * 4 + 1) * U_ + J + lo];
        cr2 = cst[(size_t)(b0 + hi * 4 + 2) * U_ + J + lo];
        cr3 = cst[(size_t)(b0 + hi * 4 + 3) * U_ + J + lo];
    }
    if (init) {
        // zero this WG's slice of the parity-0 h buffer (16b x 16j)
        h0[(size_t)(b0 + (tid >> 4)) * U_ + J + (tid & 15)] = 0;
    }

    auto gbar = [&](unsigned epoch) {
        __syncthreads();
        if (tid == 0) {
            __hip_atomic_fetch_add(&cnt[g], 1u, __ATOMIC_RELEASE, __HIP_MEMORY_SCOPE_AGENT);
            const unsigned tgt = (unsigned)WPG * epoch;
            while (__hip_atomic_load(&cnt[g], __ATOMIC_ACQUIRE, __HIP_MEMORY_SCOPE_AGENT) < tgt)
                __builtin_amdgcn_s_sleep(2);
        }
        __syncthreads();
    };
    gbar(1);

    for (int t = 0; t < CH; ++t) {
        const unsigned short* hrd = (t & 1) ? h1 : h0;
        unsigned short*       hwr = (t & 1) ? h0 : h1;

        f32x4 acc = {0.f, 0.f, 0.f, 0.f};
        #pragma unroll
        for (int kt = 0; kt < KT; ++kt) {
            const bf16x8 a = *(const bf16x8*)(hrd + (size_t)(b0 + lo) * U_ + kt * 32 + hi * 8);
            acc = __builtin_amdgcn_mfma_f32_16x16x32_bf16(a, bf[kt], acc, 0, 0, 0);
        }

        const float4 xv = *(const float4*)(xgT + ((size_t)t * NG + gcol) * 128 + b0 + hi * 4);
        const float p0 = acc[0] + xv.x;
        const float p1 = acc[1] + xv.y;
        const float p2 = acc[2] + xv.z;
        const float p3 = acc[3] + xv.w;

        if (wv != 2) {
            const int slot = (wv == 3) ? 2 : wv;    // i->0, f->1, o->2
            ex[slot][hi * 4 + 0][lo] = sigmoidf_(p0);
            ex[slot][hi * 4 + 1][lo] = sigmoidf_(p1);
            ex[slot][hi * 4 + 2][lo] = sigmoidf_(p2);
            ex[slot][hi * 4 + 3][lo] = sigmoidf_(p3);
        }
        __syncthreads();

        if (wv == 2) {
            const int jj = J + lo;
            #pragma unroll
            for (int r = 0; r < 4; ++r) {
                const int row = hi * 4 + r;
                const float pv   = (r == 0) ? p0 : (r == 1) ? p1 : (r == 2) ? p2 : p3;
                const float i_   = ex[0][row][lo];
                const float f_   = ex[1][row][lo];
                const float o_   = ex[2][row][lo];
                float& cr = (r == 0) ? cr0 : (r == 1) ? cr1 : (r == 2) ? cr2 : cr3;
                cr = f_ * cr + i_ * fmaxf(pv, 0.f);
                const float hn = o_ * fmaxf(cr, 0.f);
                const int b = b0 + row;
                hwr[(size_t)b * U_ + jj] = f2bf(hn);
                if (hseqT) hseqT[((size_t)t * U_ + jj) * 128 + b] = hn;
            }
        }
        gbar((unsigned)t + 2);
    }

    if (wv == 2) {
        cst[(size_t)(b0 + hi * 4 + 0) * U_ + J + lo] = cr0;
        cst[(size_t)(b0 + hi * 4 + 1) * U_ + J + lo] = cr1;
        cst[(size_t)(b0 + hi * 4 + 2) * U_ + J + lo] = cr2;
        cst[(size_t)(b0 + hi * 4 + 3) * U_ + J + lo] = cr3;
    }
}

// ---------------------------------------------------------------------------
// Head: out[b] = sigmoid( relu(h2[b,:] @ Wd + bd) @ Wc + bc ), h2 bf16 [128][256]
// ---------------------------------------------------------------------------
__global__ __launch_bounds__(64) void head_kernel(
    const unsigned short* __restrict__ h2,
    const float* __restrict__ Wd,
    const float* __restrict__ bd,
    const float* __restrict__ Wc,
    const float* __restrict__ bc,
    float* __restrict__ out)
{
    const int b = blockIdx.x;
    const int j = threadIdx.x;          // 0..63
    float a = bd[j];
    const unsigned short* hrow = h2 + (size_t)b * NU2;
    #pragma unroll 4
    for (int k = 0; k < NU2; ++k)
        a += bf2f(hrow[k]) * Wd[(size_t)k * NDENSE + j];
    a = fmaxf(a, 0.f) * Wc[j];
    #pragma unroll
    for (int off = 32; off > 0; off >>= 1)
        a += __shfl_down(a, off);
    if (j == 0)
        out[b] = 1.f / (1.f + expf(-(a + bc[0])));
}

// ---------------------------------------------------------------------------
extern "C" void kernel_launch(void* const* d_in, const int* in_sizes, int n_in,
                              void* d_out, int out_size, void* d_ws, size_t ws_size,
                              hipStream_t stream)
{
    const int*   tokens = (const int*)  d_in[0];
    const float* emb    = (const float*)d_in[1];
    const float* W0     = (const float*)d_in[2];
    const float* Ur0    = (const float*)d_in[3];
    const float* b0v    = (const float*)d_in[4];
    const float* W1     = (const float*)d_in[5];
    const float* Ur1    = (const float*)d_in[6];
    const float* b1v    = (const float*)d_in[7];
    const float* W2     = (const float*)d_in[8];
    const float* Ur2    = (const float*)d_in[9];
    const float* b2v    = (const float*)d_in[10];
    const float* Wd     = (const float*)d_in[11];
    const float* bd     = (const float*)d_in[12];
    const float* Wc     = (const float*)d_in[13];
    const float* bc     = (const float*)d_in[14];
    float* out = (float*)d_out;

    auto need = [](size_t ch) -> size_t {
        return ch * 2048 * 128 * 4            // xgT (worst layer)
             + ch * (256 + 512) * 128 * 4     // hs0 + hs1
             + (size_t)(4 << 20);
    };
    size_t CH = 128;
    while (CH > 8 && need(CH) > ws_size) CH >>= 1;
    const int nc = SEQT / (int)CH;

    char* p = (char*)d_ws;
    auto alloc = [&](size_t bytes) -> char* {
        char* q = p; p += (bytes + 255) & ~(size_t)255; return q;
    };
    float* xgT = (float*)alloc(CH * 2048 * 128 * 4);
    float* hs0 = (float*)alloc(CH * 256 * 128 * 4);
    float* hs1 = (float*)alloc(CH * 512 * 128 * 4);
    unsigned short* h0A = (unsigned short*)alloc(128 * NU0 * 2);
    unsigned short* h0B = (unsigned short*)alloc(128 * NU0 * 2);
    unsigned short* h1A = (unsigned short*)alloc(128 * NU1 * 2);
    unsigned short* h1B = (unsigned short*)alloc(128 * NU1 * 2);
    unsigned short* h2A = (unsigned short*)alloc(128 * NU2 * 2);
    unsigned short* h2B = (unsigned short*)alloc(128 * NU2 * 2);
    float* c0 = (float*)alloc(128 * NU0 * 4);
    float* c1 = (float*)alloc(128 * NU1 * 4);
    float* c2 = (float*)alloc(128 * NU2 * 4);
    unsigned* cnt = (unsigned*)alloc(4096);

    hipMemsetAsync(cnt, 0, 4096, stream);

    auto kA = lstm_mfma<NU0>;   // also used for layer 2 (same U)
    auto kB = lstm_mfma<NU1>;

    for (int ci = 0; ci < nc; ++ci) {
        const int t0 = ci * (int)CH;
        int init = (ci == 0) ? 1 : 0;
        int ch = (int)CH;

        // ---- layer 0 ----
        gemm_xgT<0><<<dim3((int)CH, 8), 256, 0, stream>>>(
            emb, tokens, t0, W0, b0v, xgT, 4 * NU0, EMB_D);
        {
            const float* xp = xgT; const float* up = Ur0;
            unsigned short *ha = h0A, *hb = h0B;
            float *cp = c0, *hq = hs0;
            unsigned* cp2 = cnt + (size_t)(ci * 3 + 0) * 8;
            void* args[] = {&xp, &up, &ha, &hb, &cp, &hq, &cp2, &ch, &init};
            hipLaunchCooperativeKernel((void*)kA, dim3(8 * (NU0 / 16)), dim3(256),
                                       args, 0, stream);
        }
        // ---- layer 1 ----
        gemm_xgT<1><<<dim3((int)CH, 16), 256, 0, stream>>>(
            hs0, nullptr, 0, W1, b1v, xgT, 4 * NU1, NU0);
        {
            const float* xp = xgT; const float* up = Ur1;
            unsigned short *ha = h1A, *hb = h1B;
            float *cp = c1, *hq = hs1;
            unsigned* cp2 = cnt + (size_t)(ci * 3 + 1) * 8;
            void* args[] = {&xp, &up, &ha, &hb, &cp, &hq, &cp2, &ch, &init};
            hipLaunchCooperativeKernel((void*)kB, dim3(8 * (NU1 / 16)), dim3(256),
                                       args, 0, stream);
        }
        // ---- layer 2 ----
        gemm_xgT<1><<<dim3((int)CH, 8), 256, 0, stream>>>(
            hs1, nullptr, 0, W2, b2v, xgT, 4 * NU2, NU1);
        {
            const float* xp = xgT; const float* up = Ur2;
            unsigned short *ha = h2A, *hb = h2B;
            float *cp = c2, *hq = nullptr;
            unsigned* cp2 = cnt + (size_t)(ci * 3 + 2) * 8;
            void* args[] = {&xp, &up, &ha, &hb, &cp, &hq, &cp2, &ch, &init};
            hipLaunchCooperativeKernel((void*)kA, dim3(8 * (NU2 / 16)), dim3(256),
                                       args, 0, stream);
        }
    }

    // CH even -> final layer-2 h lands in the parity-0 buffer
    head_kernel<<<BATCH, 64, 0, stream>>>(h2A, Wd, bd, Wc, bc, out);
}

// Round 5
// 13923.143 us; speedup vs baseline: 4.8113x; 1.3401x over previous
//
#include <hip/hip_runtime.h>
#include <cstdint>
#include <cstddef>

#define BATCH  128
#define SEQT   512
#define EMB_D  300
#define VOCABN 5000
#define KP0    320          // EMB_D padded to mult of 32
#define NU0    256
#define NU1    512
#define NU2    256
#define NDENSE 64

typedef unsigned short ushortT;
typedef __attribute__((ext_vector_type(8))) short bf16x8;
typedef __attribute__((ext_vector_type(8))) unsigned short u16x8;
typedef __attribute__((ext_vector_type(4))) float f32x4;

static __device__ __forceinline__ unsigned short f2bf(float x) {
    union { float f; unsigned u; } v; v.f = x;
    const unsigned r = v.u + 0x7FFFu + ((v.u >> 16) & 1u);
    return (unsigned short)(r >> 16);
}
static __device__ __forceinline__ float bf2f(unsigned short b) {
    union { unsigned u; float f; } v; v.u = ((unsigned)b) << 16;
    return v.f;
}
static __device__ __forceinline__ float sigmoidf_(float x) {
    return 1.f / (1.f + __expf(-x));
}

// ---------------------------------------------------------------------------
// One-time converts: W [K][NG] f32 -> WbfT [NG][KP] bf16 (transposed, padded);
// emb [VOCAB][300] f32 -> embbf [VOCAB][KP0] bf16 (padded).
// ---------------------------------------------------------------------------
__global__ __launch_bounds__(256) void convert_WT(
    const float* __restrict__ W, ushortT* __restrict__ WbfT,
    int K, int NG, int KP, int total)
{
    for (int idx = blockIdx.x * 256 + threadIdx.x; idx < total; idx += gridDim.x * 256) {
        const int m = idx / KP, k = idx - m * KP;
        WbfT[idx] = (k < K) ? f2bf(W[(size_t)k * NG + m]) : (ushortT)0;
    }
}
__global__ __launch_bounds__(256) void convert_emb(
    const float* __restrict__ emb, ushortT* __restrict__ embbf)
{
    const int total = VOCABN * KP0;
    for (int idx = blockIdx.x * 256 + threadIdx.x; idx < total; idx += gridDim.x * 256) {
        const int v = idx / KP0, k = idx - v * KP0;
        embbf[idx] = (k < EMB_D) ? f2bf(emb[(size_t)v * EMB_D + k]) : (ushortT)0;
    }
}

// ---------------------------------------------------------------------------
// MFMA GEMM: xgT[t][m][b] = sum_k WbfT[m][k] * x_t[b][k] + bias[m]
// A = WbfT rows (M=gate cols), B = x rows (N=batch). 16x16x32 bf16 MFMA.
// Block: 256 thr (4 waves), tile 128M x 128N, BK=32. Wave tile 32M x 128N.
// LDS tiles [row][32k] bf16 with 16B-granule XOR swizzle (g ^= (row>>1)&3).
// MODE 0: x rows gathered from embbf via tokens; MODE 1: x = hseqX slab t.
// ---------------------------------------------------------------------------
template<int MODE>
__global__ __launch_bounds__(256) void gemm_mfma(
    const ushortT* __restrict__ Bsrc,   // MODE0: embbf[VOCAB][KP]; MODE1: hseqX[CH][128][KP]
    const int*   __restrict__ tokens, int t0,
    const ushortT* __restrict__ WbfT,   // [NG][KP]
    const float* __restrict__ bias,     // [NG]
    float* __restrict__ xgT,            // [CH][NG][128]
    int NG, int KP)
{
    __shared__ ushortT Wl[128][32];
    __shared__ ushortT Xl[128][32];
    __shared__ int tokL[128];

    const int tid = threadIdx.x;
    const int t   = blockIdx.x;
    const int m0  = blockIdx.y * 128;
    const int wv  = tid >> 6;
    const int lane = tid & 63;
    const int lo  = lane & 15;
    const int hi  = lane >> 4;

    if (MODE == 0) {
        if (tid < 128) tokL[tid] = tokens[tid * SEQT + t0 + t];
        __syncthreads();
    }

    f32x4 acc[2][8];
    #pragma unroll
    for (int s = 0; s < 2; ++s)
        #pragma unroll
        for (int n = 0; n < 8; ++n)
            acc[s][n] = f32x4{0.f, 0.f, 0.f, 0.f};

    for (int k0 = 0; k0 < KP; k0 += 32) {
        #pragma unroll
        for (int it = 0; it < 2; ++it) {
            const int idx = tid + it * 256;          // 0..511
            const int row = idx >> 2, gq = idx & 3;
            const int gs  = gq ^ ((row >> 1) & 3);
            *(u16x8*)&Wl[row][gs * 8] =
                *(const u16x8*)(WbfT + (size_t)(m0 + row) * KP + k0 + gq * 8);
            const ushortT* xs;
            if (MODE == 0) xs = Bsrc + (size_t)tokL[row] * KP + k0 + gq * 8;
            else           xs = Bsrc + ((size_t)t * 128 + row) * KP + k0 + gq * 8;
            *(u16x8*)&Xl[row][gs * 8] = *(const u16x8*)xs;
        }
        __syncthreads();

        bf16x8 bfr[8];
        #pragma unroll
        for (int n = 0; n < 8; ++n) {
            const int row = n * 16 + lo;
            bfr[n] = *(const bf16x8*)&Xl[row][(hi ^ ((row >> 1) & 3)) * 8];
        }
        #pragma unroll
        for (int s = 0; s < 2; ++s) {
            const int row = wv * 32 + s * 16 + lo;
            const bf16x8 a = *(const bf16x8*)&Wl[row][(hi ^ ((row >> 1) & 3)) * 8];
            #pragma unroll
            for (int n = 0; n < 8; ++n)
                acc[s][n] = __builtin_amdgcn_mfma_f32_16x16x32_bf16(a, bfr[n], acc[s][n], 0, 0, 0);
        }
        __syncthreads();
    }

    // epilogue: C row = m (hi*4+reg), col = b (lo). Coalesced over lo.
    #pragma unroll
    for (int s = 0; s < 2; ++s) {
        #pragma unroll
        for (int j = 0; j < 4; ++j) {
            const int m = m0 + wv * 32 + s * 16 + hi * 4 + j;
            const float bi = bias[m];
            float* op = xgT + ((size_t)t * NG + m) * 128;
            #pragma unroll
            for (int n = 0; n < 8; ++n)
                op[n * 16 + lo] = acc[s][n][j] + bi;
        }
    }
}

// ---------------------------------------------------------------------------
// MFMA recurrence, XCD-local groups. Group g = blockIdx.x % 8 (round-robin
// dispatch puts all of a group's WGs on one XCD -> barrier + h traffic stay
// in that XCD's L2). Group owns 16 batch rows; WG owns 16 h-cols x 4 gates
// (one gate per wave); U cols persistent in bf16 B-fragments (registers).
// h-seq written directly as bf16 slabs [t][128][U] (= next layer's GEMM B).
// Barrier: release atomicAdd + relaxed spin + final acquire, per-group ctr.
// ---------------------------------------------------------------------------
template<int U_>
__global__ __launch_bounds__(256) void lstm_mfma(
    const float* __restrict__ xgT,     // [CH][4U][128]
    const float* __restrict__ Umat,    // [U][4U] gates i,f,c,o
    ushortT* __restrict__ h0,          // carry (seq path) / parity0 (l2) [128][U]
    ushortT* __restrict__ h1,          // parity1 (l2); == h0 otherwise
    float* __restrict__ cst,           // [128][U]
    ushortT* __restrict__ hseqX,       // [CH][128][U] bf16 or nullptr
    unsigned* __restrict__ cnt,        // [8] per-group epochs (pre-zeroed)
    int CH, int init)
{
    constexpr int NG  = 4 * U_;
    constexpr int KT  = U_ / 32;
    constexpr int WPG = U_ / 16;

    __shared__ float ex[3][16][17];

    const int tid  = threadIdx.x;
    const int wv   = tid >> 6;
    const int lane = tid & 63;
    const int lo   = lane & 15;
    const int hi   = lane >> 4;
    const int g    = blockIdx.x & 7;          // XCD-local group
    const int wgj  = blockIdx.x >> 3;
    const int J    = wgj * 16;
    const int b0   = g * 16;
    const int gcol = wv * U_ + J + lo;
    const size_t S = (size_t)128 * U_;

    // persistent B-fragments: U[:, gcol] in bf16
    bf16x8 bf[KT];
    #pragma unroll
    for (int kt = 0; kt < KT; ++kt) {
        const float* up = Umat + (size_t)(kt * 32 + hi * 8) * NG + gcol;
        bf16x8 v;
        #pragma unroll
        for (int i = 0; i < 8; ++i) v[i] = (short)f2bf(up[(size_t)i * NG]);
        bf[kt] = v;
    }

    float cr0 = 0.f, cr1 = 0.f, cr2 = 0.f, cr3 = 0.f;
    if (!init && wv == 2) {
        cr0 = cst[(size_t)(b0 + hi * 4 + 0) * U_ + J + lo];
        cr1 = cst[(size_t)(b0 + hi * 4 + 1) * U_ + J + lo];
        cr2 = cst[(size_t)(b0 + hi * 4 + 2) * U_ + J + lo];
        cr3 = cst[(size_t)(b0 + hi * 4 + 3) * U_ + J + lo];
    }
    if (init) h0[(size_t)(b0 + (tid >> 4)) * U_ + J + (tid & 15)] = 0;

    unsigned ep = 1;
    auto gbar = [&]() {
        __syncthreads();
        if (tid == 0) {
            __hip_atomic_fetch_add(&cnt[g], 1u, __ATOMIC_RELEASE, __HIP_MEMORY_SCOPE_AGENT);
            const unsigned tgt = (unsigned)WPG * ep;
            while (__hip_atomic_load(&cnt[g], __ATOMIC_RELAXED, __HIP_MEMORY_SCOPE_AGENT) < tgt)
                __builtin_amdgcn_s_sleep(1);
            (void)__hip_atomic_load(&cnt[g], __ATOMIC_ACQUIRE, __HIP_MEMORY_SCOPE_AGENT);
        }
        ++ep;
        __syncthreads();
    };
    gbar();   // U-frags + init h visible group-wide

    for (int t = 0; t < CH; ++t) {
        const ushortT* hrd;
        ushortT* hwr;
        if (hseqX) {
            hrd = t ? (hseqX + (size_t)(t - 1) * S) : h0;
            hwr = hseqX + (size_t)t * S;
        } else {
            hrd = (t & 1) ? h1 : h0;
            hwr = (t & 1) ? h0 : h1;
        }

        f32x4 acc  = {0.f, 0.f, 0.f, 0.f};
        f32x4 acc2 = {0.f, 0.f, 0.f, 0.f};
        const ushortT* hb = hrd + (size_t)(b0 + lo) * U_;
        #pragma unroll
        for (int kt = 0; kt < KT; kt += 2) {
            const bf16x8 a0 = *(const bf16x8*)(hb + kt * 32 + hi * 8);
            acc  = __builtin_amdgcn_mfma_f32_16x16x32_bf16(a0, bf[kt], acc, 0, 0, 0);
            const bf16x8 a1 = *(const bf16x8*)(hb + (kt + 1) * 32 + hi * 8);
            acc2 = __builtin_amdgcn_mfma_f32_16x16x32_bf16(a1, bf[kt + 1], acc2, 0, 0, 0);
        }
        acc = acc + acc2;

        const float4 xv = *(const float4*)(xgT + ((size_t)t * NG + gcol) * 128 + b0 + hi * 4);
        const float p0 = acc[0] + xv.x;
        const float p1 = acc[1] + xv.y;
        const float p2 = acc[2] + xv.z;
        const float p3 = acc[3] + xv.w;

        if (wv != 2) {
            const int slot = (wv == 3) ? 2 : wv;    // i->0, f->1, o->2
            ex[slot][hi * 4 + 0][lo] = sigmoidf_(p0);
            ex[slot][hi * 4 + 1][lo] = sigmoidf_(p1);
            ex[slot][hi * 4 + 2][lo] = sigmoidf_(p2);
            ex[slot][hi * 4 + 3][lo] = sigmoidf_(p3);
        }
        __syncthreads();

        if (wv == 2) {
            const int jj = J + lo;
            #pragma unroll
            for (int r = 0; r < 4; ++r) {
                const int row = hi * 4 + r;
                const float pv = (r == 0) ? p0 : (r == 1) ? p1 : (r == 2) ? p2 : p3;
                const float i_ = ex[0][row][lo];
                const float f_ = ex[1][row][lo];
                const float o_ = ex[2][row][lo];
                float& cr = (r == 0) ? cr0 : (r == 1) ? cr1 : (r == 2) ? cr2 : cr3;
                cr = f_ * cr + i_ * fmaxf(pv, 0.f);
                const float hn = o_ * fmaxf(cr, 0.f);
                const ushortT hv = f2bf(hn);
                const int b = b0 + row;
                hwr[(size_t)b * U_ + jj] = hv;
                if (hseqX && t == CH - 1) h0[(size_t)b * U_ + jj] = hv;  // carry state
            }
        }
        gbar();
    }

    if (wv == 2) {
        cst[(size_t)(b0 + hi * 4 + 0) * U_ + J + lo] = cr0;
        cst[(size_t)(b0 + hi * 4 + 1) * U_ + J + lo] = cr1;
        cst[(size_t)(b0 + hi * 4 + 2) * U_ + J + lo] = cr2;
        cst[(size_t)(b0 + hi * 4 + 3) * U_ + J + lo] = cr3;
    }
}

// ---------------------------------------------------------------------------
// Head: out[b] = sigmoid( relu(h2[b,:] @ Wd + bd) @ Wc + bc ), h2 bf16 [128][256]
// ---------------------------------------------------------------------------
__global__ __launch_bounds__(64) void head_kernel(
    const ushortT* __restrict__ h2,
    const float* __restrict__ Wd,
    const float* __restrict__ bd,
    const float* __restrict__ Wc,
    const float* __restrict__ bc,
    float* __restrict__ out)
{
    const int b = blockIdx.x;
    const int j = threadIdx.x;          // 0..63
    float a = bd[j];
    const ushortT* hrow = h2 + (size_t)b * NU2;
    #pragma unroll 4
    for (int k = 0; k < NU2; ++k)
        a += bf2f(hrow[k]) * Wd[(size_t)k * NDENSE + j];
    a = fmaxf(a, 0.f) * Wc[j];
    #pragma unroll
    for (int off = 32; off > 0; off >>= 1)
        a += __shfl_down(a, off);
    if (j == 0)
        out[b] = 1.f / (1.f + expf(-(a + bc[0])));
}

// ---------------------------------------------------------------------------
extern "C" void kernel_launch(void* const* d_in, const int* in_sizes, int n_in,
                              void* d_out, int out_size, void* d_ws, size_t ws_size,
                              hipStream_t stream)
{
    const int*   tokens = (const int*)  d_in[0];
    const float* emb    = (const float*)d_in[1];
    const float* W0     = (const float*)d_in[2];
    const float* Ur0    = (const float*)d_in[3];
    const float* b0v    = (const float*)d_in[4];
    const float* W1     = (const float*)d_in[5];
    const float* Ur1    = (const float*)d_in[6];
    const float* b1v    = (const float*)d_in[7];
    const float* W2     = (const float*)d_in[8];
    const float* Ur2    = (const float*)d_in[9];
    const float* b2v    = (const float*)d_in[10];
    const float* Wd     = (const float*)d_in[11];
    const float* bd     = (const float*)d_in[12];
    const float* Wc     = (const float*)d_in[13];
    const float* bc     = (const float*)d_in[14];
    float* out = (float*)d_out;

    auto need = [](size_t ch) -> size_t {
        return ch * 2048 * 128 * 4            // xgT (worst layer, f32)
             + ch * 128 * (256 + 512) * 2     // hseqX slabs (bf16)
             + (size_t)(16 << 20);            // converts + states + slack
    };
    size_t CH = 128;
    while (CH > 8 && need(CH) > ws_size) CH >>= 1;
    const int nc = SEQT / (int)CH;

    char* p = (char*)d_ws;
    auto alloc = [&](size_t bytes) -> char* {
        char* q = p; p += (bytes + 255) & ~(size_t)255; return q;
    };
    float*   xgT   = (float*)  alloc(CH * 2048 * 128 * 4);
    ushortT* hs0   = (ushortT*)alloc(CH * 128 * NU0 * 2);
    ushortT* hs1   = (ushortT*)alloc(CH * 128 * NU1 * 2);
    ushortT* WbfT0 = (ushortT*)alloc((size_t)4 * NU0 * KP0 * 2);
    ushortT* WbfT1 = (ushortT*)alloc((size_t)4 * NU1 * NU0 * 2);
    ushortT* WbfT2 = (ushortT*)alloc((size_t)4 * NU2 * NU1 * 2);
    ushortT* embbf = (ushortT*)alloc((size_t)VOCABN * KP0 * 2);
    ushortT* h0A   = (ushortT*)alloc(128 * NU0 * 2);
    ushortT* h1A   = (ushortT*)alloc(128 * NU1 * 2);
    ushortT* h2A   = (ushortT*)alloc(128 * NU2 * 2);
    ushortT* h2B   = (ushortT*)alloc(128 * NU2 * 2);
    float*   c0    = (float*)  alloc(128 * NU0 * 4);
    float*   c1    = (float*)  alloc(128 * NU1 * 4);
    float*   c2    = (float*)  alloc(128 * NU2 * 4);
    unsigned* cnt  = (unsigned*)alloc(4096);

    hipMemsetAsync(cnt, 0, 4096, stream);

    // one-time weight/embedding converts
    convert_WT<<<512, 256, 0, stream>>>(W0, WbfT0, EMB_D, 4 * NU0, KP0, 4 * NU0 * KP0);
    convert_WT<<<512, 256, 0, stream>>>(W1, WbfT1, NU0, 4 * NU1, NU0, 4 * NU1 * NU0);
    convert_WT<<<512, 256, 0, stream>>>(W2, WbfT2, NU1, 4 * NU2, NU1, 4 * NU2 * NU1);
    convert_emb<<<1024, 256, 0, stream>>>(emb, embbf);

    auto kA = lstm_mfma<NU0>;   // layers 0 and 2
    auto kB = lstm_mfma<NU1>;

    for (int ci = 0; ci < nc; ++ci) {
        const int t0 = ci * (int)CH;
        int init = (ci == 0) ? 1 : 0;
        int ch = (int)CH;

        // ---- layer 0 ----
        gemm_mfma<0><<<dim3((int)CH, 8), 256, 0, stream>>>(
            embbf, tokens, t0, WbfT0, b0v, xgT, 4 * NU0, KP0);
        {
            const float* xp = xgT; const float* up = Ur0;
            ushortT *ha = h0A, *hb = h0A, *hq = hs0;
            float* cp = c0;
            unsigned* cq = cnt + (size_t)(ci * 3 + 0) * 8;
            void* args[] = {&xp, &up, &ha, &hb, &cp, &hq, &cq, &ch, &init};
            hipLaunchCooperativeKernel((void*)kA, dim3(8 * (NU0 / 16)), dim3(256),
                                       args, 0, stream);
        }
        // ---- layer 1 ----
        gemm_mfma<1><<<dim3((int)CH, 16), 256, 0, stream>>>(
            hs0, nullptr, 0, WbfT1, b1v, xgT, 4 * NU1, NU0);
        {
            const float* xp = xgT; const float* up = Ur1;
            ushortT *ha = h1A, *hb = h1A, *hq = hs1;
            float* cp = c1;
            unsigned* cq = cnt + (size_t)(ci * 3 + 1) * 8;
            void* args[] = {&xp, &up, &ha, &hb, &cp, &hq, &cq, &ch, &init};
            hipLaunchCooperativeKernel((void*)kB, dim3(8 * (NU1 / 16)), dim3(256),
                                       args, 0, stream);
        }
        // ---- layer 2 ----
        gemm_mfma<1><<<dim3((int)CH, 8), 256, 0, stream>>>(
            hs1, nullptr, 0, WbfT2, b2v, xgT, 4 * NU2, NU1);
        {
            const float* xp = xgT; const float* up = Ur2;
            ushortT *ha = h2A, *hb = h2B, *hq = nullptr;
            float* cp = c2;
            unsigned* cq = cnt + (size_t)(ci * 3 + 2) * 8;
            void* args[] = {&xp, &up, &ha, &hb, &cp, &hq, &cq, &ch, &init};
            hipLaunchCooperativeKernel((void*)kA, dim3(8 * (NU2 / 16)), dim3(256),
                                       args, 0, stream);
        }
    }

    // CH even -> layer-2 final h in parity-0 buffer (h2A)
    head_kernel<<<BATCH, 64, 0, stream>>>(h2A, Wd, bd, Wc, bc, out);
}